// Round 3
// baseline (242.314 us; speedup 1.0000x reference)
//
#include <hip/hip_runtime.h>
#include <hip/hip_bf16.h>
#include <stdint.h>

// NaN-masked euclidean distances via bf16 MFMA, two-kernel pipeline.
//   prepass: X -> (xc, p) bf16 planes; Y -> (m2 = -2*yc, q) bf16 planes (d_ws)
//   main:    d_ij = sum_k [xx*q + p*yy + xc*m2], cnt_ij = sum_k p*q
//            xx = bf16(xc^2), yy = 0.25*m2^2 derived IN-REGISTER (saves 1/3 LDS BW,
//            which round-2 counters proved is the binding resource: MfmaUtil 40.3%
//            == 128 B/cy LDS peak / 317 B/cy demand).
//   out = sqrt(clip(d,0)*D/max(1,cnt)), NaN where cnt==0.
// BK=64 halves barrier count; swizzle chunk(r,kq)=r*8+(kq^(r&7)) keeps staging
// lane-sequential while fragment reads hit all 8 LDS superbanks.

typedef __bf16 bf16_t;
typedef __attribute__((ext_vector_type(8))) __bf16 bf16x8;
typedef __attribute__((ext_vector_type(4))) float floatx4;

#define NROWS 4096
#define MCOLS 4096
#define DDIM  1024
#define BM 128
#define BN 128
#define BK 64
#define PLANE_ELEMS ((size_t)NROWS * DDIM)              // 4M elems = 8 MB bf16/plane
#define WS_NEEDED   (4 * PLANE_ELEMS * sizeof(bf16_t))  // 32 MB

// ---------------- prepass: fp32 -> 4 bf16 planes ----------------
__global__ __launch_bounds__(256)
void convert_planes(const float* __restrict__ X, const float* __restrict__ Y,
                    bf16_t* __restrict__ ws) {
    bf16_t* pXC = ws;
    bf16_t* pP  = ws + PLANE_ELEMS;
    bf16_t* pM2 = ws + 2 * PLANE_ELEMS;
    bf16_t* pQ  = ws + 3 * PLANE_ELEMS;

    const size_t nx8 = PLANE_ELEMS / 8;                 // 8 elems per thread
    size_t id = (size_t)blockIdx.x * 256 + threadIdx.x;

    if (id < nx8) {
        const float4 a = ((const float4*)X)[id * 2];
        const float4 b = ((const float4*)X)[id * 2 + 1];
        const float xs[8] = {a.x, a.y, a.z, a.w, b.x, b.y, b.z, b.w};
        bf16x8 vxc, vp;
        #pragma unroll
        for (int e = 0; e < 8; e++) {
            float x = xs[e];
            bool miss = __builtin_isnan(x);
            float xc = miss ? 0.f : x;
            vxc[e] = (bf16_t)xc;
            vp[e]  = miss ? (bf16_t)0.f : (bf16_t)1.f;
        }
        ((bf16x8*)pXC)[id] = vxc;
        ((bf16x8*)pP )[id] = vp;
    } else {
        size_t j = id - nx8;
        const float4 a = ((const float4*)Y)[j * 2];
        const float4 b = ((const float4*)Y)[j * 2 + 1];
        const float ys[8] = {a.x, a.y, a.z, a.w, b.x, b.y, b.z, b.w};
        bf16x8 vm2, vq;
        #pragma unroll
        for (int e = 0; e < 8; e++) {
            float y = ys[e];
            bool miss = __builtin_isnan(y);
            float yc = miss ? 0.f : y;
            vm2[e] = (bf16_t)(-2.f * yc);
            vq[e]  = miss ? (bf16_t)0.f : (bf16_t)1.f;
        }
        ((bf16x8*)pM2)[j] = vm2;
        ((bf16x8*)pQ )[j] = vq;
    }
}

// elementwise square of a bf16x8 fragment (optionally *0.25), round-half-up repack
__device__ __forceinline__ bf16x8 sq8(bf16x8 v, bool quarter) {
    union U { bf16x8 h; uint32_t u[4]; };
    U in; in.h = v;
    U out;
    #pragma unroll
    for (int i = 0; i < 4; i++) {
        uint32_t w = in.u[i];
        float lo = __uint_as_float(w << 16);
        float hi = __uint_as_float(w & 0xFFFF0000u);
        float sl = lo * lo;
        float sh = hi * hi;
        if (quarter) { sl *= 0.25f; sh *= 0.25f; }
        uint32_t ul = (__float_as_uint(sl) + 0x8000u) >> 16;
        uint32_t uh = (__float_as_uint(sh) + 0x8000u) & 0xFFFF0000u;
        out.u[i] = uh | ul;
    }
    return out.h;
}

// ---------------- main MFMA kernel ----------------
// LDS: 4 planes of [128 rows x 64 k] bf16 = 16384 B each, 64 KB total.
// Row = 128 B = 8 chunks of 16 B. chunk(r,kq) = r*8 + (kq ^ (r&7)).
// Staging inverse: chunk C -> r = C>>3, kq = (C&7) ^ (r&7).
__global__ __launch_bounds__(256, 2)
void nan_euclid_main(const bf16_t* __restrict__ ws, float* __restrict__ out) {
    __shared__ bf16_t lds[4 * BM * BK];                 // 65536 B

    const int tid  = threadIdx.x;
    const int lane = tid & 63;
    const int wid  = tid >> 6;                          // 0..3
    const int quad = lane >> 4;                         // 0..3
    const int r16  = lane & 15;
    const int wrow = (wid >> 1) * 64;
    const int wcol = (wid & 1) * 64;

    const int blockRow = blockIdx.y * BM;
    const int blockCol = blockIdx.x * BN;

    const char* wsb  = (const char*)ws;
    char* ldsb = (char*)lds;

    // staging: 16 global_load_lds (width 16) per wave per kc
    uint32_t goff[16];
    uint32_t loff[16];
    #pragma unroll
    for (int t = 0; t < 16; t++) {
        int gi = wid * 16 + t;                          // 0..63
        int pl = gi >> 4;                               // plane 0..3
        int ii = gi & 15;                               // instr within plane
        int chunk = ii * 64 + lane;                     // 0..1023 (128 rows x 8)
        int r  = chunk >> 3;
        int kq = (chunk & 7) ^ (r & 7);
        int rowg = (pl < 2 ? blockRow : blockCol) + r;
        goff[t] = (uint32_t)((pl * PLANE_ELEMS + (size_t)rowg * DDIM + kq * 8) * 2);
        loff[t] = (uint32_t)(pl * 16384 + ii * 1024);   // +lane*16 by HW
    }

    // fragment-read LDS byte offsets, per k-step s in {0,1} (k = s*32 + quad*8 + j)
    int aswz[2][4], bswz[2][4];
    #pragma unroll
    for (int s = 0; s < 2; s++) {
        #pragma unroll
        for (int tt = 0; tt < 4; tt++) {
            int m = wrow + tt * 16 + r16;
            int kqa = s * 4 + quad;
            aswz[s][tt] = ((m * 8) + (kqa ^ (m & 7))) * 16;
            int n = wcol + tt * 16 + r16;
            bswz[s][tt] = ((n * 8) + (kqa ^ (n & 7))) * 16;
        }
    }

    floatx4 acc_d[4][4];
    floatx4 acc_c[4][4];
    #pragma unroll
    for (int i = 0; i < 4; i++)
        #pragma unroll
        for (int j = 0; j < 4; j++)
            #pragma unroll
            for (int r = 0; r < 4; r++) { acc_d[i][j][r] = 0.f; acc_c[i][j][r] = 0.f; }

    for (int kc = 0; kc < DDIM / BK; kc++) {
        #pragma unroll
        for (int t = 0; t < 16; t++) {
            __builtin_amdgcn_global_load_lds(
                (const __attribute__((address_space(1))) void*)(wsb + goff[t] + kc * (BK * 2)),
                (__attribute__((address_space(3))) void*)(ldsb + loff[t]),
                16, 0, 0);
        }
        __syncthreads();

        #pragma unroll
        for (int s = 0; s < 2; s++) {
            bf16x8 bm2[4], bq[4], byy[4];
            #pragma unroll
            for (int tn = 0; tn < 4; tn++) {
                bm2[tn] = *(const bf16x8*)(ldsb + 2 * 16384 + bswz[s][tn]);
                bq[tn]  = *(const bf16x8*)(ldsb + 3 * 16384 + bswz[s][tn]);
                byy[tn] = sq8(bm2[tn], true);           // yy = 0.25*(-2y)^2 = y^2
            }
            #pragma unroll
            for (int tm = 0; tm < 4; tm++) {
                bf16x8 axc = *(const bf16x8*)(ldsb + 0 * 16384 + aswz[s][tm]);
                bf16x8 ap  = *(const bf16x8*)(ldsb + 1 * 16384 + aswz[s][tm]);
                bf16x8 axx = sq8(axc, false);           // xx = xc^2
                #pragma unroll
                for (int tn = 0; tn < 4; tn++) {
                    acc_d[tm][tn] = __builtin_amdgcn_mfma_f32_16x16x32_bf16(axx, bq[tn],  acc_d[tm][tn], 0, 0, 0);
                    acc_d[tm][tn] = __builtin_amdgcn_mfma_f32_16x16x32_bf16(ap,  byy[tn], acc_d[tm][tn], 0, 0, 0);
                    acc_d[tm][tn] = __builtin_amdgcn_mfma_f32_16x16x32_bf16(axc, bm2[tn], acc_d[tm][tn], 0, 0, 0);
                    acc_c[tm][tn] = __builtin_amdgcn_mfma_f32_16x16x32_bf16(ap,  bq[tn],  acc_c[tm][tn], 0, 0, 0);
                }
            }
        }
        __syncthreads();
    }

    // epilogue (C/D: col=lane&15, row=quad*4+reg)
    #pragma unroll
    for (int tm = 0; tm < 4; tm++) {
        #pragma unroll
        for (int tn = 0; tn < 4; tn++) {
            int col = blockCol + wcol + tn * 16 + r16;
            #pragma unroll
            for (int r = 0; r < 4; r++) {
                int row = blockRow + wrow + tm * 16 + quad * 4 + r;
                float d = acc_d[tm][tn][r];
                float c = acc_c[tm][tn][r];
                d = fmaxf(d, 0.f);
                float res;
                if (c < 0.5f) {
                    res = __builtin_nanf("");
                } else {
                    res = __builtin_sqrtf(d * (float)DDIM / c);
                }
                out[(size_t)row * MCOLS + col] = res;
            }
        }
    }
}

// ---------------- fallback: fused single-kernel (if ws too small) ----------------
#define LDK 40
__global__ __launch_bounds__(256, 2)
void nan_euclid_fused(const float* __restrict__ X, const float* __restrict__ Y,
                      float* __restrict__ out) {
    __shared__ bf16_t s_xx[BM * LDK];
    __shared__ bf16_t s_p [BM * LDK];
    __shared__ bf16_t s_xc[BM * LDK];
    __shared__ bf16_t s_q [BN * LDK];
    __shared__ bf16_t s_yy[BN * LDK];
    __shared__ bf16_t s_m2[BN * LDK];

    typedef __attribute__((ext_vector_type(4))) __bf16 bf16x4;
    const int tid  = threadIdx.x;
    const int lane = tid & 63;
    const int wid  = tid >> 6;
    const int quad = lane >> 4;
    const int r16  = lane & 15;
    const int wrow = (wid >> 1) * 64;
    const int wcol = (wid & 1) * 64;

    const int blockRow = blockIdx.y * BM;
    const int blockCol = blockIdx.x * BN;

    floatx4 acc_d[4][4];
    floatx4 acc_c[4][4];
    #pragma unroll
    for (int i = 0; i < 4; i++)
        #pragma unroll
        for (int j = 0; j < 4; j++)
            #pragma unroll
            for (int r = 0; r < 4; r++) { acc_d[i][j][r] = 0.f; acc_c[i][j][r] = 0.f; }

    for (int kc = 0; kc < DDIM / 32; kc++) {
        const int kbase = kc * 32;
        #pragma unroll
        for (int i = 0; i < 4; i++) {
            int idx = tid + 256 * i;
            int row = idx >> 3;
            int c4  = idx & 7;
            const float4 v = *(const float4*)(X + (size_t)(blockRow + row) * DDIM + kbase + c4 * 4);
            bf16x4 vxc, vxx, vp;
            const float xs[4] = {v.x, v.y, v.z, v.w};
            #pragma unroll
            for (int e = 0; e < 4; e++) {
                float x = xs[e];
                bool miss = __builtin_isnan(x);
                float xc = miss ? 0.f : x;
                vxc[e] = (bf16_t)xc;
                vxx[e] = (bf16_t)(xc * xc);
                vp[e]  = miss ? (bf16_t)0.f : (bf16_t)1.f;
            }
            int off = row * LDK + c4 * 4;
            *(bf16x4*)&s_xc[off] = vxc;
            *(bf16x4*)&s_xx[off] = vxx;
            *(bf16x4*)&s_p [off] = vp;
        }
        #pragma unroll
        for (int i = 0; i < 4; i++) {
            int idx = tid + 256 * i;
            int row = idx >> 3;
            int c4  = idx & 7;
            const float4 v = *(const float4*)(Y + (size_t)(blockCol + row) * DDIM + kbase + c4 * 4);
            bf16x4 vq, vyy, vm2;
            const float ys[4] = {v.x, v.y, v.z, v.w};
            #pragma unroll
            for (int e = 0; e < 4; e++) {
                float y = ys[e];
                bool miss = __builtin_isnan(y);
                float yc = miss ? 0.f : y;
                vq[e]  = miss ? (bf16_t)0.f : (bf16_t)1.f;
                vyy[e] = (bf16_t)(yc * yc);
                vm2[e] = (bf16_t)(-2.f * yc);
            }
            int off = row * LDK + c4 * 4;
            *(bf16x4*)&s_q [off] = vq;
            *(bf16x4*)&s_yy[off] = vyy;
            *(bf16x4*)&s_m2[off] = vm2;
        }
        __syncthreads();
        bf16x8 bq[4], byy[4], bm2[4];
        #pragma unroll
        for (int tn = 0; tn < 4; tn++) {
            int off = (wcol + tn * 16 + r16) * LDK + quad * 8;
            bq[tn]  = *(const bf16x8*)&s_q [off];
            byy[tn] = *(const bf16x8*)&s_yy[off];
            bm2[tn] = *(const bf16x8*)&s_m2[off];
        }
        #pragma unroll
        for (int tm = 0; tm < 4; tm++) {
            int off = (wrow + tm * 16 + r16) * LDK + quad * 8;
            bf16x8 axx = *(const bf16x8*)&s_xx[off];
            bf16x8 ap  = *(const bf16x8*)&s_p [off];
            bf16x8 axc = *(const bf16x8*)&s_xc[off];
            #pragma unroll
            for (int tn = 0; tn < 4; tn++) {
                acc_d[tm][tn] = __builtin_amdgcn_mfma_f32_16x16x32_bf16(axx, bq[tn],  acc_d[tm][tn], 0, 0, 0);
                acc_d[tm][tn] = __builtin_amdgcn_mfma_f32_16x16x32_bf16(ap,  byy[tn], acc_d[tm][tn], 0, 0, 0);
                acc_d[tm][tn] = __builtin_amdgcn_mfma_f32_16x16x32_bf16(axc, bm2[tn], acc_d[tm][tn], 0, 0, 0);
                acc_c[tm][tn] = __builtin_amdgcn_mfma_f32_16x16x32_bf16(ap,  bq[tn],  acc_c[tm][tn], 0, 0, 0);
            }
        }
        __syncthreads();
    }
    #pragma unroll
    for (int tm = 0; tm < 4; tm++) {
        #pragma unroll
        for (int tn = 0; tn < 4; tn++) {
            int col = blockCol + wcol + tn * 16 + r16;
            #pragma unroll
            for (int r = 0; r < 4; r++) {
                int row = blockRow + wrow + tm * 16 + quad * 4 + r;
                float d = acc_d[tm][tn][r];
                float c = acc_c[tm][tn][r];
                d = fmaxf(d, 0.f);
                float res;
                if (c < 0.5f) {
                    res = __builtin_nanf("");
                } else {
                    res = __builtin_sqrtf(d * (float)DDIM / c);
                }
                out[(size_t)row * MCOLS + col] = res;
            }
        }
    }
}

extern "C" void kernel_launch(void* const* d_in, const int* in_sizes, int n_in,
                              void* d_out, int out_size, void* d_ws, size_t ws_size,
                              hipStream_t stream) {
    const float* X = (const float*)d_in[0];
    const float* Y = (const float*)d_in[1];
    float* out = (float*)d_out;

    if (ws_size >= WS_NEEDED) {
        bf16_t* ws = (bf16_t*)d_ws;
        const size_t total8 = 2 * PLANE_ELEMS / 8;      // 1M threads
        dim3 cgrid((unsigned)((total8 + 255) / 256));
        convert_planes<<<cgrid, 256, 0, stream>>>(X, Y, ws);
        dim3 grid(MCOLS / BN, NROWS / BM);
        nan_euclid_main<<<grid, dim3(256), 0, stream>>>(ws, out);
    } else {
        dim3 grid(MCOLS / BN, NROWS / BM);
        nan_euclid_fused<<<grid, dim3(256), 0, stream>>>(X, Y, out);
    }
}

// Round 4
// 210.767 us; speedup vs baseline: 1.1497x; 1.1497x over previous
//
#include <hip/hip_runtime.h>
#include <hip/hip_bf16.h>
#include <stdint.h>

// NaN-masked euclidean distances via mixed bf16/fp8 MFMA, two-kernel pipeline.
//   prepass: X -> xc(bf16), xx(fp8), p(fp8); Y -> m2=-2y(bf16), yy(fp8), q(fp8)
//   main:    d_ij = sum_k [xx*q + p*yy + xc*m2]  (xx*q, p*yy, p*q in fp8 MFMA;
//            xc*m2 in bf16 MFMA), cnt_ij = sum_k p*q (exact: 0/1 products).
//   out = sqrt(clip(d,0)*D/max(1,cnt)), NaN where cnt==0.
// Rationale (R2/R3 counters): kernel is LDS-*read*-BW bound (R2 MfmaUtil 40.3%
// == 128 B/cy / (8 waves * 24 KB / 614 cyc)); R3's in-register derivation
// flipped it VALU-bound (51% VALUBusy). fp8 planes cut fragment reads to
// 16 KB/wave per 32-k with ZERO added VALU -> predicted cap 61%.

typedef __bf16 bf16_t;
typedef __attribute__((ext_vector_type(8))) __bf16 bf16x8;
typedef __attribute__((ext_vector_type(4))) float floatx4;

#define NROWS 4096
#define MCOLS 4096
#define DDIM  1024
#define BM 128
#define BN 128
#define BK 64
#define PLANE_ELEMS ((size_t)NROWS * DDIM)   // 4M elems
// ws byte layout: XC bf16 @0 (8MB) | M2 bf16 @8MB | XX fp8 @16MB | P @20MB | YY @24MB | Q @28MB
#define WS_XC  ((size_t)0)
#define WS_M2  ((size_t)8  << 20)
#define WS_XX  ((size_t)16 << 20)
#define WS_P   ((size_t)20 << 20)
#define WS_YY  ((size_t)24 << 20)
#define WS_Q   ((size_t)28 << 20)
#define WS_NEEDED ((size_t)32 << 20)

// pack 8 floats to 8 fp8 e4m3 bytes (2 dwords) via HW packed cvt
__device__ __forceinline__ void pk_fp8x8(const float* f, uint32_t* out2) {
    int r0 = __builtin_amdgcn_cvt_pk_fp8_f32(f[0], f[1], 0, 0);
    r0     = __builtin_amdgcn_cvt_pk_fp8_f32(f[2], f[3], r0, 1);
    int r1 = __builtin_amdgcn_cvt_pk_fp8_f32(f[4], f[5], 0, 0);
    r1     = __builtin_amdgcn_cvt_pk_fp8_f32(f[6], f[7], r1, 1);
    out2[0] = (uint32_t)r0; out2[1] = (uint32_t)r1;
}

// ---------------- prepass: fp32 -> 2 bf16 + 4 fp8 planes ----------------
__global__ __launch_bounds__(256)
void convert_planes(const float* __restrict__ X, const float* __restrict__ Y,
                    char* __restrict__ ws) {
    const size_t nx8 = PLANE_ELEMS / 8;      // threads per input, 8 elems each
    size_t id = (size_t)blockIdx.x * 256 + threadIdx.x;

    if (id < nx8) {
        const float4 a = ((const float4*)X)[id * 2];
        const float4 b = ((const float4*)X)[id * 2 + 1];
        const float xs[8] = {a.x, a.y, a.z, a.w, b.x, b.y, b.z, b.w};
        bf16x8 vxc;
        float fxx[8], fp[8];
        #pragma unroll
        for (int e = 0; e < 8; e++) {
            float x = xs[e];
            bool miss = __builtin_isnan(x);
            float xc = miss ? 0.f : x;
            vxc[e] = (bf16_t)xc;
            fxx[e] = xc * xc;
            fp[e]  = miss ? 0.f : 1.f;
        }
        uint32_t uxx[2], up[2];
        pk_fp8x8(fxx, uxx);
        pk_fp8x8(fp,  up);
        ((bf16x8*)(ws + WS_XC))[id] = vxc;
        ((uint2*)(ws + WS_XX))[id] = make_uint2(uxx[0], uxx[1]);
        ((uint2*)(ws + WS_P ))[id] = make_uint2(up[0],  up[1]);
    } else {
        size_t j = id - nx8;
        const float4 a = ((const float4*)Y)[j * 2];
        const float4 b = ((const float4*)Y)[j * 2 + 1];
        const float ys[8] = {a.x, a.y, a.z, a.w, b.x, b.y, b.z, b.w};
        bf16x8 vm2;
        float fyy[8], fq[8];
        #pragma unroll
        for (int e = 0; e < 8; e++) {
            float y = ys[e];
            bool miss = __builtin_isnan(y);
            float yc = miss ? 0.f : y;
            vm2[e] = (bf16_t)(-2.f * yc);
            fyy[e] = yc * yc;
            fq[e]  = miss ? 0.f : 1.f;
        }
        uint32_t uyy[2], uq[2];
        pk_fp8x8(fyy, uyy);
        pk_fp8x8(fq,  uq);
        ((bf16x8*)(ws + WS_M2))[j] = vm2;
        ((uint2*)(ws + WS_YY))[j] = make_uint2(uyy[0], uyy[1]);
        ((uint2*)(ws + WS_Q ))[j] = make_uint2(uq[0],  uq[1]);
    }
}

// ---------------- main MFMA kernel ----------------
// LDS: XC,M2 bf16 [128x64] 16KB each; XX,P,YY,Q fp8 [128x64] 8KB each = 64KB.
// bf16 swizzle (16B chunks, 8/row): chunk(r,kq)=r*8+(kq^(r&7))   [R3-verified, 0 conflicts]
// fp8 swizzle (16B chunks, 4/row):  chunk(r,kq16)=r*4+(kq16^s4(r)), s4(r)=(r+(r>>2))&3
//   -> b64 fragment reads are uniformly 4-per-bank = b64 minimum cycles (free).
#define L_XC 0
#define L_M2 16384
#define L_XX 32768
#define L_P  40960
#define L_YY 49152
#define L_Q  57344

__global__ __launch_bounds__(256, 2)
void nan_euclid_main(const char* __restrict__ ws, float* __restrict__ out) {
    __shared__ char ldsb[65536];

    const int tid  = threadIdx.x;
    const int lane = tid & 63;
    const int wid  = tid >> 6;               // 0..3
    const int quad = lane >> 4;              // 0..3
    const int r16  = lane & 15;
    const int wrow = (wid >> 1) * 64;
    const int wcol = (wid & 1) * 64;

    const int blockRow = blockIdx.y * BM;
    const int blockCol = blockIdx.x * BN;

    // ---- staging precompute: 16 global_load_lds (width 16) per wave per kc ----
    uint32_t goff[16];   // ws byte offset at kc=0
    uint32_t loff[16];   // LDS byte offset (wave-uniform; +lane*16 by HW)
    uint32_t kadv[16];   // byte advance per kc
    #pragma unroll
    for (int t = 0; t < 16; t++) {
        int gi = wid * 16 + t;               // 0..63
        if (gi < 32) {
            // bf16 planes: XC (gi 0..15), M2 (gi 16..31)
            int pl = gi >> 4;                // 0=XC(X rows), 1=M2(Y rows)
            int ii = gi & 15;
            int c  = ii * 64 + lane;         // 16B chunk, 128 rows x 8
            int r  = c >> 3;
            int kq = (c & 7) ^ (r & 7);
            int rowg = (pl == 0 ? blockRow : blockCol) + r;
            size_t base = (pl == 0 ? WS_XC : WS_M2);
            goff[t] = (uint32_t)(base + ((size_t)rowg * DDIM + kq * 8) * 2);
            loff[t] = (uint32_t)((pl == 0 ? L_XC : L_M2) + ii * 1024);
            kadv[t] = BK * 2;
        } else {
            // fp8 planes: XX (32..39), P (40..47), YY (48..55), Q (56..63)
            int pl = (gi - 32) >> 3;         // 0=XX,1=P (X rows); 2=YY,3=Q (Y rows)
            int ii = gi & 7;
            int c  = ii * 64 + lane;         // 16B chunk, 128 rows x 4
            int r  = c >> 2;
            int s4 = (r + (r >> 2)) & 3;
            int kq16 = (c & 3) ^ s4;
            int rowg = (pl < 2 ? blockRow : blockCol) + r;
            size_t base = (pl == 0 ? WS_XX : pl == 1 ? WS_P : pl == 2 ? WS_YY : WS_Q);
            int lb = (pl == 0 ? L_XX : pl == 1 ? L_P : pl == 2 ? L_YY : L_Q);
            goff[t] = (uint32_t)(base + (size_t)rowg * DDIM + kq16 * 16);
            loff[t] = (uint32_t)(lb + ii * 1024);
            kadv[t] = BK;
        }
    }

    // ---- fragment-read LDS offsets per k-step s in {0,1} (k = s*32 + quad*8 + j) ----
    int a16[2][4], b16[2][4];   // bf16 (b128) offsets within plane
    int a8[2][4],  b8[2][4];    // fp8  (b64)  offsets within plane
    #pragma unroll
    for (int s = 0; s < 2; s++) {
        int kq8  = s * 4 + quad;
        int kq16 = s * 2 + (quad >> 1);
        int half = (quad & 1) * 8;
        #pragma unroll
        for (int tt = 0; tt < 4; tt++) {
            int m = wrow + tt * 16 + r16;
            a16[s][tt] = ((m * 8) + (kq8 ^ (m & 7))) * 16;
            a8[s][tt]  = m * 64 + ((kq16 ^ ((m + (m >> 2)) & 3)) * 16) + half;
            int n = wcol + tt * 16 + r16;
            b16[s][tt] = ((n * 8) + (kq8 ^ (n & 7))) * 16;
            b8[s][tt]  = n * 64 + ((kq16 ^ ((n + (n >> 2)) & 3)) * 16) + half;
        }
    }

    floatx4 acc_d[4][4];
    floatx4 acc_c[4][4];
    #pragma unroll
    for (int i = 0; i < 4; i++)
        #pragma unroll
        for (int j = 0; j < 4; j++)
            #pragma unroll
            for (int r = 0; r < 4; r++) { acc_d[i][j][r] = 0.f; acc_c[i][j][r] = 0.f; }

    for (int kc = 0; kc < DDIM / BK; kc++) {
        #pragma unroll
        for (int t = 0; t < 16; t++) {
            __builtin_amdgcn_global_load_lds(
                (const __attribute__((address_space(1))) void*)(ws + goff[t] + kc * kadv[t]),
                (__attribute__((address_space(3))) void*)(ldsb + loff[t]),
                16, 0, 0);
        }
        __syncthreads();

        #pragma unroll
        for (int s = 0; s < 2; s++) {
            bf16x8 bm2[4]; int64_t byy[4], bq[4];
            #pragma unroll
            for (int tn = 0; tn < 4; tn++) {
                bm2[tn] = *(const bf16x8*)(ldsb + L_M2 + b16[s][tn]);
                byy[tn] = *(const int64_t*)(ldsb + L_YY + b8[s][tn]);
                bq[tn]  = *(const int64_t*)(ldsb + L_Q  + b8[s][tn]);
            }
            #pragma unroll
            for (int tm = 0; tm < 4; tm++) {
                bf16x8 axc  = *(const bf16x8*)(ldsb + L_XC + a16[s][tm]);
                int64_t axx = *(const int64_t*)(ldsb + L_XX + a8[s][tm]);
                int64_t ap  = *(const int64_t*)(ldsb + L_P  + a8[s][tm]);
                #pragma unroll
                for (int tn = 0; tn < 4; tn++) {
                    acc_d[tm][tn] = __builtin_amdgcn_mfma_f32_16x16x32_fp8_fp8(axx, bq[tn],  acc_d[tm][tn], 0, 0, 0);
                    acc_d[tm][tn] = __builtin_amdgcn_mfma_f32_16x16x32_fp8_fp8(ap,  byy[tn], acc_d[tm][tn], 0, 0, 0);
                    acc_d[tm][tn] = __builtin_amdgcn_mfma_f32_16x16x32_bf16   (axc, bm2[tn], acc_d[tm][tn], 0, 0, 0);
                    acc_c[tm][tn] = __builtin_amdgcn_mfma_f32_16x16x32_fp8_fp8(ap,  bq[tn],  acc_c[tm][tn], 0, 0, 0);
                }
            }
        }
        __syncthreads();
    }

    // ---- epilogue (C/D: col=lane&15, row=quad*4+reg) ----
    #pragma unroll
    for (int tm = 0; tm < 4; tm++) {
        #pragma unroll
        for (int tn = 0; tn < 4; tn++) {
            int col = blockCol + wcol + tn * 16 + r16;
            #pragma unroll
            for (int r = 0; r < 4; r++) {
                int row = blockRow + wrow + tm * 16 + quad * 4 + r;
                float d = acc_d[tm][tn][r];
                float c = acc_c[tm][tn][r];
                d = fmaxf(d, 0.f);
                float res;
                if (c < 0.5f) {
                    res = __builtin_nanf("");
                } else {
                    res = __builtin_sqrtf(d * (float)DDIM / c);
                }
                out[(size_t)row * MCOLS + col] = res;
            }
        }
    }
}

// ---------------- fallback: fused single-kernel (if ws too small) ----------------
#define LDK 40
__global__ __launch_bounds__(256, 2)
void nan_euclid_fused(const float* __restrict__ X, const float* __restrict__ Y,
                      float* __restrict__ out) {
    typedef __attribute__((ext_vector_type(4))) __bf16 bf16x4;
    __shared__ bf16_t s_xx[BM * LDK];
    __shared__ bf16_t s_p [BM * LDK];
    __shared__ bf16_t s_xc[BM * LDK];
    __shared__ bf16_t s_q [BN * LDK];
    __shared__ bf16_t s_yy[BN * LDK];
    __shared__ bf16_t s_m2[BN * LDK];

    const int tid  = threadIdx.x;
    const int lane = tid & 63;
    const int wid  = tid >> 6;
    const int quad = lane >> 4;
    const int r16  = lane & 15;
    const int wrow = (wid >> 1) * 64;
    const int wcol = (wid & 1) * 64;
    const int blockRow = blockIdx.y * BM;
    const int blockCol = blockIdx.x * BN;

    floatx4 acc_d[4][4];
    floatx4 acc_c[4][4];
    #pragma unroll
    for (int i = 0; i < 4; i++)
        #pragma unroll
        for (int j = 0; j < 4; j++)
            #pragma unroll
            for (int r = 0; r < 4; r++) { acc_d[i][j][r] = 0.f; acc_c[i][j][r] = 0.f; }

    for (int kc = 0; kc < DDIM / 32; kc++) {
        const int kbase = kc * 32;
        #pragma unroll
        for (int i = 0; i < 4; i++) {
            int idx = tid + 256 * i;
            int row = idx >> 3;
            int c4  = idx & 7;
            const float4 v = *(const float4*)(X + (size_t)(blockRow + row) * DDIM + kbase + c4 * 4);
            bf16x4 vxc, vxx, vp;
            const float xs[4] = {v.x, v.y, v.z, v.w};
            #pragma unroll
            for (int e = 0; e < 4; e++) {
                float x = xs[e];
                bool miss = __builtin_isnan(x);
                float xc = miss ? 0.f : x;
                vxc[e] = (bf16_t)xc;
                vxx[e] = (bf16_t)(xc * xc);
                vp[e]  = miss ? (bf16_t)0.f : (bf16_t)1.f;
            }
            int off = row * LDK + c4 * 4;
            *(bf16x4*)&s_xc[off] = vxc;
            *(bf16x4*)&s_xx[off] = vxx;
            *(bf16x4*)&s_p [off] = vp;
        }
        #pragma unroll
        for (int i = 0; i < 4; i++) {
            int idx = tid + 256 * i;
            int row = idx >> 3;
            int c4  = idx & 7;
            const float4 v = *(const float4*)(Y + (size_t)(blockCol + row) * DDIM + kbase + c4 * 4);
            bf16x4 vq, vyy, vm2;
            const float ys[4] = {v.x, v.y, v.z, v.w};
            #pragma unroll
            for (int e = 0; e < 4; e++) {
                float y = ys[e];
                bool miss = __builtin_isnan(y);
                float yc = miss ? 0.f : y;
                vq[e]  = miss ? (bf16_t)0.f : (bf16_t)1.f;
                vyy[e] = (bf16_t)(yc * yc);
                vm2[e] = (bf16_t)(-2.f * yc);
            }
            int off = row * LDK + c4 * 4;
            *(bf16x4*)&s_q [off] = vq;
            *(bf16x4*)&s_yy[off] = vyy;
            *(bf16x4*)&s_m2[off] = vm2;
        }
        __syncthreads();
        bf16x8 bq[4], byy[4], bm2[4];
        #pragma unroll
        for (int tn = 0; tn < 4; tn++) {
            int off = (wcol + tn * 16 + r16) * LDK + quad * 8;
            bq[tn]  = *(const bf16x8*)&s_q [off];
            byy[tn] = *(const bf16x8*)&s_yy[off];
            bm2[tn] = *(const bf16x8*)&s_m2[off];
        }
        #pragma unroll
        for (int tm = 0; tm < 4; tm++) {
            int off = (wrow + tm * 16 + r16) * LDK + quad * 8;
            bf16x8 axx = *(const bf16x8*)&s_xx[off];
            bf16x8 ap  = *(const bf16x8*)&s_p [off];
            bf16x8 axc = *(const bf16x8*)&s_xc[off];
            #pragma unroll
            for (int tn = 0; tn < 4; tn++) {
                acc_d[tm][tn] = __builtin_amdgcn_mfma_f32_16x16x32_bf16(axx, bq[tn],  acc_d[tm][tn], 0, 0, 0);
                acc_d[tm][tn] = __builtin_amdgcn_mfma_f32_16x16x32_bf16(ap,  byy[tn], acc_d[tm][tn], 0, 0, 0);
                acc_d[tm][tn] = __builtin_amdgcn_mfma_f32_16x16x32_bf16(axc, bm2[tn], acc_d[tm][tn], 0, 0, 0);
                acc_c[tm][tn] = __builtin_amdgcn_mfma_f32_16x16x32_bf16(ap,  bq[tn],  acc_c[tm][tn], 0, 0, 0);
            }
        }
        __syncthreads();
    }
    #pragma unroll
    for (int tm = 0; tm < 4; tm++) {
        #pragma unroll
        for (int tn = 0; tn < 4; tn++) {
            int col = blockCol + wcol + tn * 16 + r16;
            #pragma unroll
            for (int r = 0; r < 4; r++) {
                int row = blockRow + wrow + tm * 16 + quad * 4 + r;
                float d = acc_d[tm][tn][r];
                float c = acc_c[tm][tn][r];
                d = fmaxf(d, 0.f);
                float res = (c < 0.5f) ? __builtin_nanf("")
                                       : __builtin_sqrtf(d * (float)DDIM / c);
                out[(size_t)row * MCOLS + col] = res;
            }
        }
    }
}

extern "C" void kernel_launch(void* const* d_in, const int* in_sizes, int n_in,
                              void* d_out, int out_size, void* d_ws, size_t ws_size,
                              hipStream_t stream) {
    const float* X = (const float*)d_in[0];
    const float* Y = (const float*)d_in[1];
    float* out = (float*)d_out;

    if (ws_size >= WS_NEEDED) {
        char* ws = (char*)d_ws;
        const size_t total8 = 2 * PLANE_ELEMS / 8;
        dim3 cgrid((unsigned)((total8 + 255) / 256));
        convert_planes<<<cgrid, 256, 0, stream>>>(X, Y, ws);
        dim3 grid(MCOLS / BN, NROWS / BM);
        nan_euclid_main<<<grid, dim3(256), 0, stream>>>(ws, out);
    } else {
        dim3 grid(MCOLS / BN, NROWS / BM);
        nan_euclid_fused<<<grid, dim3(256), 0, stream>>>(X, Y, out);
    }
}

// Round 6
// 166.861 us; speedup vs baseline: 1.4522x; 1.2631x over previous
//
#include <hip/hip_runtime.h>
#include <hip/hip_bf16.h>
#include <stdint.h>

// NaN-masked euclidean distances via MX-scaled all-fp8 MFMA (unity scales).
//   prepass: X -> xc, xx, p (fp8 e4m3); Y -> m2=-2y, yy, q (fp8 e4m3)
//            stored pre-swizzled (16B-chunk XOR perm within 64B k-group) so main
//            staging is an identity global_load_lds copy.
//   main:    d = xx*q + p*yy + xc*m2 ; cnt = p*q  (fp8 0/1 products -> exact)
//            all four chains: v_mfma_scale_f32_32x32x64_f8f6f4 cbsz=0 blgp=0 (fp8/fp8),
//            scales 0x7f (=1.0). Mirrored A/B load formulas -> k-mapping guess cancels
//            (m148-verified pattern). 32x32 C/D layout per m74/m101.
//   out = sqrt(clip(d,0)*D/max(1,cnt)), NaN where cnt==0.
// R5 post-mortem: fp4 p/q operand layout was the failure; all-fp8 removes it.
// MFMA floor 29.3us (137.4 GFLOP @ 4686 TF MX ubench); LDS reads sub-dominant.

typedef __bf16 bf16_t;
typedef __attribute__((ext_vector_type(8))) __bf16 bf16x8;
typedef __attribute__((ext_vector_type(4))) float floatx4;
typedef __attribute__((ext_vector_type(16))) float floatx16;
typedef __attribute__((ext_vector_type(8))) int int32x8;

#define NROWS 4096
#define MCOLS 4096
#define DDIM  1024
#define BM 128
#define BN 128
#define BK 64

// ws layout: 6 fp8 planes x 4 MB (row = 1024 B, pre-swizzled chunks)
#define WS_XX ((uint32_t)0)
#define WS_XC ((uint32_t)(4  << 20))
#define WS_P  ((uint32_t)(8  << 20))
#define WS_YY ((uint32_t)(12 << 20))
#define WS_M2 ((uint32_t)(16 << 20))
#define WS_Q  ((uint32_t)(20 << 20))
#define WS_NEEDED ((size_t)(24 << 20))

// LDS plane bases: 6 planes x 8192 B ([128 rows x 64 B])
#define L_XX 0
#define L_XC 8192
#define L_P  16384
#define L_YY 24576
#define L_M2 32768
#define L_Q  40960

// ---------------- prepass: fp32 -> 6 fp8 planes, pre-swizzled ----------------
// 2048 blocks x 256 thr; blocks [0,1024)->X, [1024,2048)->Y; 4 rows/block, 16 elems/thread.
__global__ __launch_bounds__(256)
void convert_planes_mx(const float* __restrict__ X, const float* __restrict__ Y,
                       char* __restrict__ ws) {
    int b = blockIdx.x;
    bool isX = (b < 1024);
    const float* src = isX ? X : Y;
    int rb = isX ? b : b - 1024;
    int row = rb * 4 + (threadIdx.x >> 6);
    int l = threadIdx.x & 63;
    int k0 = l << 4;

    const float4* p = (const float4*)(src + (size_t)row * DDIM + k0);
    float v[16];
    #pragma unroll
    for (int i = 0; i < 4; i++) {
        float4 t = p[i];
        v[4*i+0] = t.x; v[4*i+1] = t.y; v[4*i+2] = t.z; v[4*i+3] = t.w;
    }
    float fa[16], fb[16], fm[16];   // fa: xc or -2y ; fb: x^2 or y^2 ; fm: present mask
    #pragma unroll
    for (int i = 0; i < 16; i++) {
        float x = v[i];
        bool miss = __builtin_isnan(x);
        float c = miss ? 0.f : x;
        fb[i] = c * c;
        fa[i] = isX ? c : (-2.f * c);
        fm[i] = miss ? 0.f : 1.f;
    }
    uint32_t da[4], db[4], dm[4];
    #pragma unroll
    for (int i = 0; i < 4; i++) {
        int r = __builtin_amdgcn_cvt_pk_fp8_f32(fa[4*i], fa[4*i+1], 0, 0);
        r     = __builtin_amdgcn_cvt_pk_fp8_f32(fa[4*i+2], fa[4*i+3], r, 1);
        da[i] = (uint32_t)r;
        int s = __builtin_amdgcn_cvt_pk_fp8_f32(fb[4*i], fb[4*i+1], 0, 0);
        s     = __builtin_amdgcn_cvt_pk_fp8_f32(fb[4*i+2], fb[4*i+3], s, 1);
        db[i] = (uint32_t)s;
        int m = __builtin_amdgcn_cvt_pk_fp8_f32(fm[4*i], fm[4*i+1], 0, 0);
        m     = __builtin_amdgcn_cvt_pk_fp8_f32(fm[4*i+2], fm[4*i+3], m, 1);
        dm[i] = (uint32_t)m;
    }
    // 16B chunk swizzle inside each 64B k-group: phys = logical ^ ((row>>1)&3)
    uint32_t off8 = (uint32_t)row * 1024u + (uint32_t)(l >> 2) * 64u
                  + (uint32_t)((((l & 3) ^ ((row >> 1) & 3)) << 4));
    uint4 A = make_uint4(da[0], da[1], da[2], da[3]);
    uint4 B = make_uint4(db[0], db[1], db[2], db[3]);
    uint4 M = make_uint4(dm[0], dm[1], dm[2], dm[3]);
    if (isX) {
        *(uint4*)(ws + WS_XC + off8) = A;
        *(uint4*)(ws + WS_XX + off8) = B;
        *(uint4*)(ws + WS_P  + off8) = M;
    } else {
        *(uint4*)(ws + WS_M2 + off8) = A;
        *(uint4*)(ws + WS_YY + off8) = B;
        *(uint4*)(ws + WS_Q  + off8) = M;
    }
}

// ---------------- main MX MFMA kernel ----------------
__device__ __forceinline__ int32x8 ld32B(const char* p0, const char* p1) {
    union { int32x8 v; int4 h[2]; } u;
    u.h[0] = *(const int4*)p0;
    u.h[1] = *(const int4*)p1;
    return u.v;
}

__global__ __launch_bounds__(256, 2)
void nan_euclid_mx(const char* __restrict__ ws, float* __restrict__ out) {
    __shared__ __align__(16) char ldsb[49152];

    const int tid = threadIdx.x, lane = tid & 63, wid = tid >> 6;
    const int l31 = lane & 31, kh = lane >> 5;
    const int wrow = (wid >> 1) * 64, wcol = (wid & 1) * 64;
    const int blockRow = blockIdx.y * BM, blockCol = blockIdx.x * BN;

    // staging: 12 global_load_lds (16B) per wave per kc; identity copy (ws pre-swizzled)
    // global chunk id ch in [0,3072): plane = ch>>9 (XX,XC,P,YY,M2,Q), c2 = ch&511,
    // row = c2>>2, cc = c2&3. LDS byte = ch*16.
    uint32_t goff[12];
    #pragma unroll
    for (int t = 0; t < 12; t++) {
        int ch = (wid * 12 + t) * 64 + lane;
        int pl = ch >> 9;
        int c2 = ch & 511;
        int row = c2 >> 2, cc = c2 & 3;
        int rg = (pl < 3 ? blockRow : blockCol) + row;
        uint32_t base = (pl == 0) ? WS_XX : (pl == 1) ? WS_XC : (pl == 2) ? WS_P
                      : (pl == 3) ? WS_YY : (pl == 4) ? WS_M2 : WS_Q;
        goff[t] = base + (uint32_t)rg * 1024u + (uint32_t)(cc << 4);
    }

    // fragment-read LDS offsets (within plane); operand = 32 k-elems at k-half kh
    // logical quarters 2kh, 2kh+1; physical = logical ^ ((m>>1)&3)
    int aoff0[2], aoff1[2], boff0[2], boff1[2];
    #pragma unroll
    for (int tt = 0; tt < 2; tt++) {
        int m = wrow + tt * 32 + l31;
        int sw = (m >> 1) & 3;
        aoff0[tt] = m * 64 + (((kh * 2)     ^ sw) << 4);
        aoff1[tt] = m * 64 + (((kh * 2 + 1) ^ sw) << 4);
        int n = wcol + tt * 32 + l31;
        int swn = (n >> 1) & 3;
        boff0[tt] = n * 64 + (((kh * 2)     ^ swn) << 4);
        boff1[tt] = n * 64 + (((kh * 2 + 1) ^ swn) << 4);
    }

    floatx16 acc_d[2][2], acc_c[2][2];
    #pragma unroll
    for (int i = 0; i < 2; i++)
        #pragma unroll
        for (int j = 0; j < 2; j++)
            #pragma unroll
            for (int r = 0; r < 16; r++) { acc_d[i][j][r] = 0.f; acc_c[i][j][r] = 0.f; }

    for (int kc = 0; kc < DDIM / BK; kc++) {
        #pragma unroll
        for (int t = 0; t < 12; t++) {
            __builtin_amdgcn_global_load_lds(
                (const __attribute__((address_space(1))) void*)(ws + goff[t] + kc * 64u),
                (__attribute__((address_space(3))) void*)(ldsb + (uint32_t)((wid * 12 + t) * 1024)),
                16, 0, 0);
        }
        __syncthreads();

        int32x8 axx[2], axc[2], ap[2], byy[2], bm2[2], bq[2];
        #pragma unroll
        for (int tt = 0; tt < 2; tt++) {
            axx[tt] = ld32B(ldsb + L_XX + aoff0[tt], ldsb + L_XX + aoff1[tt]);
            axc[tt] = ld32B(ldsb + L_XC + aoff0[tt], ldsb + L_XC + aoff1[tt]);
            ap [tt] = ld32B(ldsb + L_P  + aoff0[tt], ldsb + L_P  + aoff1[tt]);
            byy[tt] = ld32B(ldsb + L_YY + boff0[tt], ldsb + L_YY + boff1[tt]);
            bm2[tt] = ld32B(ldsb + L_M2 + boff0[tt], ldsb + L_M2 + boff1[tt]);
            bq [tt] = ld32B(ldsb + L_Q  + boff0[tt], ldsb + L_Q  + boff1[tt]);
        }

        // chain-major order: dependency distance 4 insts per accumulator
        #pragma unroll
        for (int tm = 0; tm < 2; tm++)
            #pragma unroll
            for (int tn = 0; tn < 2; tn++)
                acc_d[tm][tn] = __builtin_amdgcn_mfma_scale_f32_32x32x64_f8f6f4(
                    axx[tm], bq[tn], acc_d[tm][tn], 0, 0, 0, 0x7f7f7f7f, 0, 0x7f7f7f7f);
        #pragma unroll
        for (int tm = 0; tm < 2; tm++)
            #pragma unroll
            for (int tn = 0; tn < 2; tn++)
                acc_d[tm][tn] = __builtin_amdgcn_mfma_scale_f32_32x32x64_f8f6f4(
                    ap[tm], byy[tn], acc_d[tm][tn], 0, 0, 0, 0x7f7f7f7f, 0, 0x7f7f7f7f);
        #pragma unroll
        for (int tm = 0; tm < 2; tm++)
            #pragma unroll
            for (int tn = 0; tn < 2; tn++)
                acc_d[tm][tn] = __builtin_amdgcn_mfma_scale_f32_32x32x64_f8f6f4(
                    axc[tm], bm2[tn], acc_d[tm][tn], 0, 0, 0, 0x7f7f7f7f, 0, 0x7f7f7f7f);
        #pragma unroll
        for (int tm = 0; tm < 2; tm++)
            #pragma unroll
            for (int tn = 0; tn < 2; tn++)
                acc_c[tm][tn] = __builtin_amdgcn_mfma_scale_f32_32x32x64_f8f6f4(
                    ap[tm], bq[tn], acc_c[tm][tn], 0, 0, 0, 0x7f7f7f7f, 0, 0x7f7f7f7f);

        __syncthreads();
    }

    // epilogue; 32x32 C/D layout (m74/m101): col = lane&31, row = (reg&3)+8*(reg>>2)+4*(lane>>5)
    #pragma unroll
    for (int tm = 0; tm < 2; tm++) {
        #pragma unroll
        for (int tn = 0; tn < 2; tn++) {
            int col = blockCol + wcol + tn * 32 + l31;
            #pragma unroll
            for (int r = 0; r < 16; r++) {
                int rowl = (r & 3) + 8 * (r >> 2) + 4 * kh;
                int row = blockRow + wrow + tm * 32 + rowl;
                float d = fmaxf(acc_d[tm][tn][r], 0.f);
                float c = acc_c[tm][tn][r];
                float res = (c < 0.5f) ? __builtin_nanf("")
                                       : __builtin_sqrtf(d * (float)DDIM / c);
                out[(size_t)row * MCOLS + col] = res;
            }
        }
    }
}

// ---------------- fallback: fused single-kernel bf16 (if ws too small) ----------------
#define LDK 40
__global__ __launch_bounds__(256, 2)
void nan_euclid_fused(const float* __restrict__ X, const float* __restrict__ Y,
                      float* __restrict__ out) {
    typedef __attribute__((ext_vector_type(4))) __bf16 bf16x4;
    __shared__ bf16_t s_xx[BM * LDK];
    __shared__ bf16_t s_p [BM * LDK];
    __shared__ bf16_t s_xc[BM * LDK];
    __shared__ bf16_t s_q [BN * LDK];
    __shared__ bf16_t s_yy[BN * LDK];
    __shared__ bf16_t s_m2[BN * LDK];

    const int tid  = threadIdx.x;
    const int lane = tid & 63;
    const int wid  = tid >> 6;
    const int quad = lane >> 4;
    const int r16  = lane & 15;
    const int wrow = (wid >> 1) * 64;
    const int wcol = (wid & 1) * 64;
    const int blockRow = blockIdx.y * BM;
    const int blockCol = blockIdx.x * BN;

    floatx4 acc_d[4][4];
    floatx4 acc_c[4][4];
    #pragma unroll
    for (int i = 0; i < 4; i++)
        #pragma unroll
        for (int j = 0; j < 4; j++)
            #pragma unroll
            for (int r = 0; r < 4; r++) { acc_d[i][j][r] = 0.f; acc_c[i][j][r] = 0.f; }

    for (int kc = 0; kc < DDIM / 32; kc++) {
        const int kbase = kc * 32;
        #pragma unroll
        for (int i = 0; i < 4; i++) {
            int idx = tid + 256 * i;
            int row = idx >> 3;
            int c4  = idx & 7;
            const float4 v = *(const float4*)(X + (size_t)(blockRow + row) * DDIM + kbase + c4 * 4);
            bf16x4 vxc, vxx, vp;
            const float xs[4] = {v.x, v.y, v.z, v.w};
            #pragma unroll
            for (int e = 0; e < 4; e++) {
                float x = xs[e];
                bool miss = __builtin_isnan(x);
                float xc = miss ? 0.f : x;
                vxc[e] = (bf16_t)xc;
                vxx[e] = (bf16_t)(xc * xc);
                vp[e]  = miss ? (bf16_t)0.f : (bf16_t)1.f;
            }
            int off = row * LDK + c4 * 4;
            *(bf16x4*)&s_xc[off] = vxc;
            *(bf16x4*)&s_xx[off] = vxx;
            *(bf16x4*)&s_p [off] = vp;
        }
        #pragma unroll
        for (int i = 0; i < 4; i++) {
            int idx = tid + 256 * i;
            int row = idx >> 3;
            int c4  = idx & 7;
            const float4 v = *(const float4*)(Y + (size_t)(blockCol + row) * DDIM + kbase + c4 * 4);
            bf16x4 vq, vyy, vm2;
            const float ys[4] = {v.x, v.y, v.z, v.w};
            #pragma unroll
            for (int e = 0; e < 4; e++) {
                float y = ys[e];
                bool miss = __builtin_isnan(y);
                float yc = miss ? 0.f : y;
                vq[e]  = miss ? (bf16_t)0.f : (bf16_t)1.f;
                vyy[e] = (bf16_t)(yc * yc);
                vm2[e] = (bf16_t)(-2.f * yc);
            }
            int off = row * LDK + c4 * 4;
            *(bf16x4*)&s_q [off] = vq;
            *(bf16x4*)&s_yy[off] = vyy;
            *(bf16x4*)&s_m2[off] = vm2;
        }
        __syncthreads();
        bf16x8 bq[4], byy[4], bm2[4];
        #pragma unroll
        for (int tn = 0; tn < 4; tn++) {
            int off = (wcol + tn * 16 + r16) * LDK + quad * 8;
            bq[tn]  = *(const bf16x8*)&s_q [off];
            byy[tn] = *(const bf16x8*)&s_yy[off];
            bm2[tn] = *(const bf16x8*)&s_m2[off];
        }
        #pragma unroll
        for (int tm = 0; tm < 4; tm++) {
            int off = (wrow + tm * 16 + r16) * LDK + quad * 8;
            bf16x8 axx = *(const bf16x8*)&s_xx[off];
            bf16x8 ap  = *(const bf16x8*)&s_p [off];
            bf16x8 axc = *(const bf16x8*)&s_xc[off];
            #pragma unroll
            for (int tn = 0; tn < 4; tn++) {
                acc_d[tm][tn] = __builtin_amdgcn_mfma_f32_16x16x32_bf16(axx, bq[tn],  acc_d[tm][tn], 0, 0, 0);
                acc_d[tm][tn] = __builtin_amdgcn_mfma_f32_16x16x32_bf16(ap,  byy[tn], acc_d[tm][tn], 0, 0, 0);
                acc_d[tm][tn] = __builtin_amdgcn_mfma_f32_16x16x32_bf16(axc, bm2[tn], acc_d[tm][tn], 0, 0, 0);
                acc_c[tm][tn] = __builtin_amdgcn_mfma_f32_16x16x32_bf16(ap,  bq[tn],  acc_c[tm][tn], 0, 0, 0);
            }
        }
        __syncthreads();
    }
    #pragma unroll
    for (int tm = 0; tm < 4; tm++) {
        #pragma unroll
        for (int tn = 0; tn < 4; tn++) {
            int col = blockCol + wcol + tn * 16 + r16;
            #pragma unroll
            for (int r = 0; r < 4; r++) {
                int row = blockRow + wrow + tm * 16 + quad * 4 + r;
                float d = acc_d[tm][tn][r];
                float c = acc_c[tm][tn][r];
                d = fmaxf(d, 0.f);
                float res = (c < 0.5f) ? __builtin_nanf("")
                                       : __builtin_sqrtf(d * (float)DDIM / c);
                out[(size_t)row * MCOLS + col] = res;
            }
        }
    }
}

extern "C" void kernel_launch(void* const* d_in, const int* in_sizes, int n_in,
                              void* d_out, int out_size, void* d_ws, size_t ws_size,
                              hipStream_t stream) {
    const float* X = (const float*)d_in[0];
    const float* Y = (const float*)d_in[1];
    float* out = (float*)d_out;

    if (ws_size >= WS_NEEDED) {
        char* ws = (char*)d_ws;
        convert_planes_mx<<<dim3(2048), dim3(256), 0, stream>>>(X, Y, ws);
        dim3 grid(MCOLS / BN, NROWS / BM);
        nan_euclid_mx<<<grid, dim3(256), 0, stream>>>(ws, out);
    } else {
        dim3 grid(MCOLS / BN, NROWS / BM);
        nan_euclid_fused<<<grid, dim3(256), 0, stream>>>(X, Y, out);
    }
}